// Round 3
// baseline (95.930 us; speedup 1.0000x reference)
//
#include <hip/hip_runtime.h>
#include <hip/hip_bf16.h>

#define GAMMA 0.1f
#define ETA   0.3f

typedef __attribute__((ext_vector_type(8))) short short8;
typedef __attribute__((ext_vector_type(4))) float f32x4;

#define ITERS 2   // 64-row chunks per wave

union BF8 { short8 s8; int i[4]; };

__device__ __forceinline__ int pack_bf2(float lo, float hi) {
    __hip_bfloat162 p = __float22bfloat162_rn(float2{lo, hi});  // v_cvt_pk_bf16_f32
    return *reinterpret_cast<int*>(&p);
}

// Each wave handles ITERS*64 rows. Per 64-row chunk: lane l computes
// perm/temp/total for row base+l (coalesced stream stores), then 4 m-tiles of
// 16 rows through MFMA with SWAPPED operands (d = mfma(W2^T, h, d)) so
// lane&15 = output ROW -> LN reduces with just xor16+xor32. b2 rides in the
// MFMA C-init. h = relu(perm*u + temp*v + b1), u=W1[0]+W1[2], v=W1[1]+W1[2]
// (feats is rank-2). All weights register-resident; no LDS, no barriers.
__global__ __launch_bounds__(256) void market_impact_mfma(
    const float* __restrict__ os_g, const float* __restrict__ liq_g,
    const float* __restrict__ W1,  const float* __restrict__ b1g,
    const float* __restrict__ W2,  const float* __restrict__ b2,
    const float* __restrict__ lnw, const float* __restrict__ lnb,
    float* __restrict__ out, int B)
{
    const int tid  = threadIdx.x;
    const int lane = tid & 63;
    const int g    = lane >> 4;   // k-group (0..3)
    const int c    = lane & 15;   // A row = output col (within 16-block); B col = data row

    // ---- one-time per-lane weights ----
    float u[16], v[16], bb[16];
    #pragma unroll
    for (int kc = 0; kc < 2; ++kc)
        #pragma unroll
        for (int j = 0; j < 8; ++j) {
            int k = kc * 32 + g * 8 + j;
            float w0 = W1[k], w1 = W1[64 + k], w2r = W1[128 + k];
            u[kc * 8 + j]  = w0 + w2r;
            v[kc * 8 + j]  = w1 + w2r;
            bb[kc * 8 + j] = b1g[k];
        }

    // W2^T fragments (A-operand): lane m=c is output col within block cc,
    // element j <-> k = kc*32 + g*8 + j.
    short8 wfrag[2][2];
    #pragma unroll
    for (int kc = 0; kc < 2; ++kc)
        #pragma unroll
        for (int cc = 0; cc < 2; ++cc) {
            BF8 t;
            #pragma unroll
            for (int jj = 0; jj < 4; ++jj) {
                int k0 = kc * 32 + g * 8 + 2 * jj;
                t.i[jj] = pack_bf2(W2[k0 * 32 + cc * 16 + c],
                                   W2[(k0 + 1) * 32 + cc * 16 + c]);
            }
            wfrag[kc][cc] = t.s8;
        }

    // epilogue constants: this lane's output cols are cc*16 + g*4 + reg
    float b2a[8], lnwa[8], lnba[8];
    #pragma unroll
    for (int cc = 0; cc < 2; ++cc) {
        float4 bq = *reinterpret_cast<const float4*>(b2  + cc * 16 + g * 4);
        float4 wq = *reinterpret_cast<const float4*>(lnw + cc * 16 + g * 4);
        float4 bl = *reinterpret_cast<const float4*>(lnb + cc * 16 + g * 4);
        b2a[cc*4+0] = bq.x; b2a[cc*4+1] = bq.y; b2a[cc*4+2] = bq.z; b2a[cc*4+3] = bq.w;
        lnwa[cc*4+0] = wq.x; lnwa[cc*4+1] = wq.y; lnwa[cc*4+2] = wq.z; lnwa[cc*4+3] = wq.w;
        lnba[cc*4+0] = bl.x; lnba[cc*4+1] = bl.y; lnba[cc*4+2] = bl.z; lnba[cc*4+3] = bl.w;
    }

    const long long wid = (long long)blockIdx.x * 4 + (tid >> 6);
    float* enc = out + 3LL * B;

    #pragma unroll 1
    for (int it = 0; it < ITERS; ++it) {
        long long base = (wid * ITERS + it) * 64;
        if (base >= B) break;                      // wave-uniform

        int r  = (int)base + lane;
        bool ok = r < B;
        float o  = ok ? os_g[r]  : 0.f;
        float lq = ok ? liq_g[r] : 1.f;
        // fast-approx rcp/rsq/sqrt: rel err ~1e-6, threshold is 6.4e-2
        float perm = GAMMA * o * __builtin_amdgcn_rcpf(lq);
        float temp = ETA * copysignf(__builtin_amdgcn_sqrtf(fabsf(o)), o)
                         * __builtin_amdgcn_rsqf(lq);
        float tot  = perm + temp;
        if (ok) {
            out[r]         = perm;
            out[B + r]     = temp;
            out[2 * B + r] = tot;
        }

        // batch all cross-lane reads up front (overlap bpermute latency)
        float pmv[4], tmv[4];
        #pragma unroll
        for (int mt = 0; mt < 4; ++mt) {
            pmv[mt] = __shfl(perm, mt * 16 + c);
            tmv[mt] = __shfl(temp, mt * 16 + c);
        }

        #pragma unroll
        for (int mt = 0; mt < 4; ++mt) {
            float pm = pmv[mt], tm = tmv[mt];
            // B-operand: h for row base + mt*16 + c, k = kc*32 + g*8 + j
            BF8 a0u, a1u;
            #pragma unroll
            for (int jj = 0; jj < 4; ++jj) {
                int j0 = 2 * jj;
                float h00 = fmaxf(0.f, fmaf(pm, u[j0],   fmaf(tm, v[j0],   bb[j0])));
                float h01 = fmaxf(0.f, fmaf(pm, u[j0+1], fmaf(tm, v[j0+1], bb[j0+1])));
                float h10 = fmaxf(0.f, fmaf(pm, u[8+j0],   fmaf(tm, v[8+j0],   bb[8+j0])));
                float h11 = fmaxf(0.f, fmaf(pm, u[8+j0+1], fmaf(tm, v[8+j0+1], bb[8+j0+1])));
                a0u.i[jj] = pack_bf2(h00, h01);
                a1u.i[jj] = pack_bf2(h10, h11);
            }

            // b2 rides in the accumulator init (exact: C-in of MFMA)
            f32x4 d0 = {b2a[0], b2a[1], b2a[2], b2a[3]};
            f32x4 d1 = {b2a[4], b2a[5], b2a[6], b2a[7]};
            d0 = __builtin_amdgcn_mfma_f32_16x16x32_bf16(wfrag[0][0], a0u.s8, d0, 0, 0, 0);
            d0 = __builtin_amdgcn_mfma_f32_16x16x32_bf16(wfrag[1][0], a1u.s8, d0, 0, 0, 0);
            d1 = __builtin_amdgcn_mfma_f32_16x16x32_bf16(wfrag[0][1], a0u.s8, d1, 0, 0, 0);
            d1 = __builtin_amdgcn_mfma_f32_16x16x32_bf16(wfrag[1][1], a1u.s8, d1, 0, 0, 0);

            // LN over 32 cols: lane holds row (base+mt*16+c), cols cc*16+g*4+reg
            float s = 0.f, q = 0.f;
            #pragma unroll
            for (int reg = 0; reg < 4; ++reg) {
                s += d0[reg];            q = fmaf(d0[reg], d0[reg], q);
                s += d1[reg];            q = fmaf(d1[reg], d1[reg], q);
            }
            s += __shfl_xor(s, 16); s += __shfl_xor(s, 32);
            q += __shfl_xor(q, 16); q += __shfl_xor(q, 32);
            float mu   = s * 0.03125f;
            float var  = fmaf(q, 0.03125f, -mu * mu);
            float rstd = __builtin_amdgcn_rsqf(var + 1e-5f);

            int row = (int)base + mt * 16 + c;
            if (row < B) {
                float4 o0, o1;
                o0.x = fmaf((d0[0] - mu) * rstd, lnwa[0], lnba[0]);
                o0.y = fmaf((d0[1] - mu) * rstd, lnwa[1], lnba[1]);
                o0.z = fmaf((d0[2] - mu) * rstd, lnwa[2], lnba[2]);
                o0.w = fmaf((d0[3] - mu) * rstd, lnwa[3], lnba[3]);
                o1.x = fmaf((d1[0] - mu) * rstd, lnwa[4], lnba[4]);
                o1.y = fmaf((d1[1] - mu) * rstd, lnwa[5], lnba[5]);
                o1.z = fmaf((d1[2] - mu) * rstd, lnwa[6], lnba[6]);
                o1.w = fmaf((d1[3] - mu) * rstd, lnwa[7], lnba[7]);
                float* rp = enc + (long long)row * 32;
                *reinterpret_cast<float4*>(rp + g * 4)      = o0;
                *reinterpret_cast<float4*>(rp + 16 + g * 4) = o1;
            }
        }
    }
}

extern "C" void kernel_launch(void* const* d_in, const int* in_sizes, int n_in,
                              void* d_out, int out_size, void* d_ws, size_t ws_size,
                              hipStream_t stream) {
    const float* os_g = (const float*)d_in[0];
    const float* liq  = (const float*)d_in[1];
    const float* W1   = (const float*)d_in[2];
    const float* b1   = (const float*)d_in[3];
    const float* W2   = (const float*)d_in[4];
    const float* b2   = (const float*)d_in[5];
    const float* lnw  = (const float*)d_in[6];
    const float* lnb  = (const float*)d_in[7];
    float* out = (float*)d_out;
    const int B = in_sizes[0];

    const int rows_per_block = 4 * ITERS * 64;   // 4 waves * ITERS chunks * 64 rows
    const int grid = (B + rows_per_block - 1) / rows_per_block;
    market_impact_mfma<<<grid, 256, 0, stream>>>(
        os_g, liq, W1, b1, W2, b2, lnw, lnb, out, B);
}